// Round 9
// baseline (1038.803 us; speedup 1.0000x reference)
//
#include <hip/hip_runtime.h>
#include <hip/hip_bf16.h>
#include <hip/hip_cooperative_groups.h>

namespace cg = cooperative_groups;

#define N_NODES 100000
#define N_EDGES 1600000
#define IN_FEAT 256
#define HID_F   128
#define OUT_FT  64

#define NBUK   256
#define NPB    391      // nodes per bucket: 256*391 = 100096 >= N
#define BUKCAP 8192     // mean 6250, sigma ~79 -> +24 sigma, safe
#define EPB    2048     // edges per bin block
#define G_BIN  ((N_EDGES + EPB - 1) / EPB)  // 782
#define G_GEMM ((N_NODES + 63) / 64)        // 1563, 64-row tiles
#define G_CAST ((IN_FEAT * HID_F + HID_F * OUT_FT + 255) / 256)  // 160
#define G_AGG  ((N_NODES + 7) / 8)          // 12500, 2 nodes per wave

typedef unsigned short u16;
typedef __attribute__((ext_vector_type(8))) unsigned short u16x8;
typedef __attribute__((ext_vector_type(8))) short short8;
typedef __attribute__((ext_vector_type(4))) float f32x4;

static __device__ inline u16 f2bf(float f) {
    __hip_bfloat16 h = __float2bfloat16(f);
    return *reinterpret_cast<u16*>(&h);
}
static __device__ inline float bf2f(u16 u) {
    union { unsigned u; float f; } c;
    c.u = ((unsigned)u) << 16;
    return c.f;
}

// ================= device phase bodies (shared by mega and fallback) =================

// ---- phase: bin edges by dst bucket (+ weight cast piggyback) ----
// pairs entry PACKED: (dstLocal << 17) | src
static __device__ __forceinline__ void dev_bin(int vb, int t, int* lh,
        const int* __restrict__ srcA, const int* __restrict__ dstA,
        int* __restrict__ gcur, unsigned* __restrict__ pairs,
        const float* __restrict__ W1, const float* __restrict__ W2,
        u16* __restrict__ W1t, u16* __restrict__ W2t) {
    if (vb >= G_BIN) {
        int idx = (vb - G_BIN) * 256 + t;
        if (idx < IN_FEAT * HID_F) {
            int k = idx / HID_F, n = idx % HID_F;
            W1t[n * IN_FEAT + k] = f2bf(W1[idx]);
        } else {
            int e2 = idx - IN_FEAT * HID_F;
            if (e2 < HID_F * OUT_FT) {
                int k = e2 / OUT_FT, n = e2 % OUT_FT;
                W2t[n * HID_F + k] = f2bf(W2[e2]);
            }
        }
        return;
    }
    __syncthreads();          // smem reuse guard (prev virtual block)
    int e0 = vb * EPB;
    if (t < NBUK) lh[t] = 0;
    __syncthreads();
#pragma unroll
    for (int i = 0; i < EPB / 256; i++) {
        int e = e0 + i * 256 + t;
        if (e < N_EDGES) atomicAdd(&lh[dstA[e] / NPB], 1);
    }
    __syncthreads();
    if (t < NBUK) {
        int c = lh[t];
        lh[t] = atomicAdd(&gcur[t], c);  // this block's base within bucket t
    }
    __syncthreads();
#pragma unroll
    for (int i = 0; i < EPB / 256; i++) {
        int e = e0 + i * 256 + t;
        if (e < N_EDGES) {
            int d = dstA[e];
            int b = d / NPB;
            int p = atomicAdd(&lh[b], 1);
            if (p < BUKCAP) {
                unsigned packed = ((unsigned)(d - b * NPB) << 17) | (unsigned)srcA[e];
                pairs[(size_t)b * BUKCAP + p] = packed;
            }
        }
    }
}

// ---- phase: per-bucket CSR fill + offsets + dinv (256 threads) ----
static __device__ __forceinline__ void dev_fillB(int b, int t, int* shm,
        const unsigned* __restrict__ pairs, const int* __restrict__ gcnt,
        int* __restrict__ offsets, float* __restrict__ dinv, int* __restrict__ csr) {
    int* hist = shm;            // NPB ints
    int* sm   = shm + NPB;      // 256 ints
    int* seb  = shm + NPB + 256;
    __syncthreads();            // smem reuse guard
    int nbase = b * NPB;
    int nn = min(NPB, N_NODES - nbase);

    // exclusive scan over 256 bucket counts
    int gv = gcnt[t];
    sm[t] = gv;
    __syncthreads();
    for (int o = 1; o < 256; o <<= 1) {
        int u = (t >= o) ? sm[t - o] : 0;
        __syncthreads();
        sm[t] += u;
        __syncthreads();
    }
    if (t == b) *seb = sm[t] - gv;
    __syncthreads();
    int ebase = *seb;
    int cnt = gcnt[b];
    const unsigned* pb = pairs + (size_t)b * BUKCAP;

    for (int i = t; i < NPB; i += 256) hist[i] = 0;
    __syncthreads();
    for (int i = t; i < cnt; i += 256) atomicAdd(&hist[pb[i] >> 17], 1);
    __syncthreads();

    // exclusive scan over hist[0..nn): thread t owns nodes [2t, 2t+2)
    int base2 = t * 2;
    int c0 = (base2 < NPB) ? hist[base2] : 0;
    int c1 = (base2 + 1 < NPB) ? hist[base2 + 1] : 0;
    int s = c0 + c1;
    __syncthreads();
    sm[t] = s;
    __syncthreads();
    for (int o = 1; o < 256; o <<= 1) {
        int u = (t >= o) ? sm[t - o] : 0;
        __syncthreads();
        sm[t] += u;
        __syncthreads();
    }
    int run = ebase + sm[t] - s;
    __syncthreads();
    int cc[2] = {c0, c1};
#pragma unroll
    for (int q = 0; q < 2; q++) {
        int n = base2 + q;
        if (n < nn) {
            int g = nbase + n;
            offsets[g] = run;
            dinv[g] = rsqrtf((float)(cc[q] + 1));  // +1 self loop
            hist[n] = run;                          // placement cursor
            run += cc[q];
        }
    }
    __syncthreads();
    for (int i = t; i < cnt; i += 256) {
        unsigned e = pb[i];
        int p = atomicAdd(&hist[e >> 17], 1);
        csr[p] = (int)(e & 0x1FFFFu);
    }
    if (b == NBUK - 1 && t == 0) offsets[N_NODES] = N_EDGES;
}

// ---- phase: GEMM layer 1 (64-row tiles, dbuf LDS, 1 barrier/step, reg prefetch) ----
static __device__ __forceinline__ void dev_gemm1(int vb, int tid, char* smem,
        const float* __restrict__ A, const u16* __restrict__ Bt,
        const float* __restrict__ dinv, u16* __restrict__ C) {
    u16 (*As)[64][40]  = (u16 (*)[64][40])smem;           // 10240 B
    u16 (*Bs)[128][40] = (u16 (*)[128][40])(smem + 10240); // 20480 B
    __syncthreads();            // smem reuse guard
    int wv = tid >> 6, lane = tid & 63;
    int m16 = lane & 15, quad = lane >> 4;
    int row0 = vb * 64;

    int ar = tid >> 2, aq = tid & 3;
    int br = tid >> 1, bh = tid & 1;
    int arow_g = row0 + ar;
    if (arow_g >= N_NODES) arow_g = N_NODES - 1;   // clamp, stores guarded
    const float* ap = &A[(size_t)arow_g * IN_FEAT + aq * 8];
    const u16*   bp = &Bt[(size_t)br * IN_FEAT + bh * 16];

    f32x4 acc[8];
#pragma unroll
    for (int j = 0; j < 8; j++) acc[j] = (f32x4)(0.f);

    {
        f32x4 a0 = *(const f32x4*)&ap[0];
        f32x4 a1 = *(const f32x4*)&ap[4];
        u16x8 b0 = *(const u16x8*)&bp[0];
        u16x8 b1 = *(const u16x8*)&bp[8];
        u16x8 av;
#pragma unroll
        for (int j = 0; j < 4; j++) { av[j] = f2bf(a0[j]); av[4 + j] = f2bf(a1[j]); }
        *(u16x8*)&As[0][ar][aq * 8] = av;
        *(u16x8*)&Bs[0][br][bh * 16] = b0;
        *(u16x8*)&Bs[0][br][bh * 16 + 8] = b1;
    }

#pragma unroll
    for (int s = 0; s < 8; s++) {
        const int buf = s & 1;
        f32x4 na0, na1; u16x8 nb0, nb1;
        if (s + 1 < 8) {
            int k0 = (s + 1) * 32;
            na0 = *(const f32x4*)&ap[k0];
            na1 = *(const f32x4*)&ap[k0 + 4];
            nb0 = *(const u16x8*)&bp[k0];
            nb1 = *(const u16x8*)&bp[k0 + 8];
        }
        __syncthreads();   // buf ready (written before this barrier)
        short8 af = *(const short8*)&As[buf][wv * 16 + m16][quad * 8];
#pragma unroll
        for (int ct = 0; ct < 8; ct++) {
            short8 bf = *(const short8*)&Bs[buf][16 * ct + m16][quad * 8];
            acc[ct] = __builtin_amdgcn_mfma_f32_16x16x32_bf16(af, bf, acc[ct], 0, 0, 0);
        }
        if (s + 1 < 8) {
            u16x8 av;
#pragma unroll
            for (int j = 0; j < 4; j++) { av[j] = f2bf(na0[j]); av[4 + j] = f2bf(na1[j]); }
            *(u16x8*)&As[buf ^ 1][ar][aq * 8] = av;
            *(u16x8*)&Bs[buf ^ 1][br][bh * 16] = nb0;
            *(u16x8*)&Bs[buf ^ 1][br][bh * 16 + 8] = nb1;
        }
    }

#pragma unroll
    for (int r4 = 0; r4 < 4; r4++) {
        int grow = row0 + wv * 16 + quad * 4 + r4;
        if (grow < N_NODES) {
            float dv = dinv[grow];
#pragma unroll
            for (int ct = 0; ct < 8; ct++)
                C[(size_t)grow * HID_F + 16 * ct + m16] = f2bf(acc[ct][r4] * dv);
        }
    }
}

// ---- phase: GEMM layer 2 (same structure, K=128) ----
static __device__ __forceinline__ void dev_gemm2(int vb, int tid, char* smem,
        const u16* __restrict__ A, const u16* __restrict__ Bt,
        const float* __restrict__ dinv, u16* __restrict__ C) {
    u16 (*As)[64][40] = (u16 (*)[64][40])smem;            // 10240 B
    u16 (*Bs)[64][40] = (u16 (*)[64][40])(smem + 10240);  // 10240 B
    __syncthreads();            // smem reuse guard
    int wv = tid >> 6, lane = tid & 63;
    int m16 = lane & 15, quad = lane >> 4;
    int row0 = vb * 64;

    int ar = tid >> 2, aq = tid & 3;
    int arow_g = row0 + ar;
    if (arow_g >= N_NODES) arow_g = N_NODES - 1;
    const u16* ap = &A[(size_t)arow_g * HID_F + aq * 8];
    const u16* bp = &Bt[(size_t)ar * HID_F + aq * 8];

    f32x4 acc[4];
#pragma unroll
    for (int j = 0; j < 4; j++) acc[j] = (f32x4)(0.f);

    {
        u16x8 a0 = *(const u16x8*)&ap[0];
        u16x8 b0 = *(const u16x8*)&bp[0];
        *(u16x8*)&As[0][ar][aq * 8] = a0;
        *(u16x8*)&Bs[0][ar][aq * 8] = b0;
    }

#pragma unroll
    for (int s = 0; s < 4; s++) {
        const int buf = s & 1;
        u16x8 na, nb;
        if (s + 1 < 4) {
            int k0 = (s + 1) * 32;
            na = *(const u16x8*)&ap[k0];
            nb = *(const u16x8*)&bp[k0];
        }
        __syncthreads();
        short8 af = *(const short8*)&As[buf][wv * 16 + m16][quad * 8];
#pragma unroll
        for (int ct = 0; ct < 4; ct++) {
            short8 bf = *(const short8*)&Bs[buf][16 * ct + m16][quad * 8];
            acc[ct] = __builtin_amdgcn_mfma_f32_16x16x32_bf16(af, bf, acc[ct], 0, 0, 0);
        }
        if (s + 1 < 4) {
            *(u16x8*)&As[buf ^ 1][ar][aq * 8] = na;
            *(u16x8*)&Bs[buf ^ 1][ar][aq * 8] = nb;
        }
    }

#pragma unroll
    for (int r4 = 0; r4 < 4; r4++) {
        int grow = row0 + wv * 16 + quad * 4 + r4;
        if (grow < N_NODES) {
            float dv = dinv[grow];
#pragma unroll
            for (int ct = 0; ct < 4; ct++)
                C[(size_t)grow * OUT_FT + 16 * ct + m16] = f2bf(acc[ct][r4] * dv);
        }
    }
}

// ---- phase: aggregation layer 1 (2 nodes/wave, 4 gathers in flight) ----
static __device__ __forceinline__ void dev_agg1(int vb, int tid,
        const u16* __restrict__ hs, const int* __restrict__ offsets,
        const int* __restrict__ csr, const float* __restrict__ dinv,
        const float* __restrict__ b, u16* __restrict__ out) {
    int wave = tid >> 6;
    int lane = tid & 63;
    int half = lane >> 5;
    int node = vb * 8 + wave * 2 + half;
    if (node >= N_NODES) return;
    int gl = lane & 31;
    int g = gl >> 4;
    int fl = gl & 15;
    const int fo = fl * 8;
    int beg = offsets[node], end = offsets[node + 1];

    float accA[8], accB[8];
#pragma unroll
    for (int i = 0; i < 8; i++) { accA[i] = 0.f; accB[i] = 0.f; }

    int j = beg;
    for (; j + 8 <= end; j += 8) {
        int s0 = csr[j + g];
        int s1 = csr[j + 2 + g];
        int s2 = csr[j + 4 + g];
        int s3 = csr[j + 6 + g];
        u16x8 r0 = *(const u16x8*)&hs[(size_t)s0 * HID_F + fo];
        u16x8 r1 = *(const u16x8*)&hs[(size_t)s1 * HID_F + fo];
        u16x8 r2 = *(const u16x8*)&hs[(size_t)s2 * HID_F + fo];
        u16x8 r3 = *(const u16x8*)&hs[(size_t)s3 * HID_F + fo];
#pragma unroll
        for (int i = 0; i < 8; i++) {
            accA[i] += bf2f(r0[i]) + bf2f(r1[i]);
            accB[i] += bf2f(r2[i]) + bf2f(r3[i]);
        }
    }
    if (j + 4 <= end) {
        int s0 = csr[j + g];
        int s1 = csr[j + 2 + g];
        u16x8 r0 = *(const u16x8*)&hs[(size_t)s0 * HID_F + fo];
        u16x8 r1 = *(const u16x8*)&hs[(size_t)s1 * HID_F + fo];
#pragma unroll
        for (int i = 0; i < 8; i++) accA[i] += bf2f(r0[i]) + bf2f(r1[i]);
        j += 4;
    }
    for (; j < end; j += 2) {
        int idx = j + g;
        if (idx < end) {
            int s = csr[idx];
            u16x8 r0 = *(const u16x8*)&hs[(size_t)s * HID_F + fo];
#pragma unroll
            for (int i = 0; i < 8; i++) accB[i] += bf2f(r0[i]);
        }
    }
#pragma unroll
    for (int i = 0; i < 8; i++) {
        float v = accA[i] + accB[i];
        v += __shfl_xor(v, 16, 64);
        accA[i] = v;
    }
    if (g == 0) {
        u16x8 sr = *(const u16x8*)&hs[(size_t)node * HID_F + fo];
        float dv = dinv[node];
        f32x4 b0 = *(const f32x4*)&b[fo];
        f32x4 b1 = *(const f32x4*)&b[fo + 4];
        u16x8 o;
#pragma unroll
        for (int i = 0; i < 4; i++) {
            o[i]     = f2bf(fmaxf(dv * (accA[i]     + bf2f(sr[i]))     + b0[i], 0.f));
            o[4 + i] = f2bf(fmaxf(dv * (accA[4 + i] + bf2f(sr[4 + i])) + b1[i], 0.f));
        }
        *(u16x8*)&out[(size_t)node * HID_F + fo] = o;
    }
}

// ---- phase: aggregation layer 2 (fp32 out) ----
static __device__ __forceinline__ void dev_agg2(int vb, int tid,
        const u16* __restrict__ hs, const int* __restrict__ offsets,
        const int* __restrict__ csr, const float* __restrict__ dinv,
        const float* __restrict__ b, float* __restrict__ out) {
    int wave = tid >> 6;
    int lane = tid & 63;
    int half = lane >> 5;
    int node = vb * 8 + wave * 2 + half;
    if (node >= N_NODES) return;
    int gl = lane & 31;
    int g = gl >> 3;
    int fl = gl & 7;
    const int fo = fl * 8;
    int beg = offsets[node], end = offsets[node + 1];

    float accA[8], accB[8];
#pragma unroll
    for (int i = 0; i < 8; i++) { accA[i] = 0.f; accB[i] = 0.f; }

    int j = beg;
    for (; j + 16 <= end; j += 16) {
        int s0 = csr[j + g];
        int s1 = csr[j + 4 + g];
        int s2 = csr[j + 8 + g];
        int s3 = csr[j + 12 + g];
        u16x8 r0 = *(const u16x8*)&hs[(size_t)s0 * OUT_FT + fo];
        u16x8 r1 = *(const u16x8*)&hs[(size_t)s1 * OUT_FT + fo];
        u16x8 r2 = *(const u16x8*)&hs[(size_t)s2 * OUT_FT + fo];
        u16x8 r3 = *(const u16x8*)&hs[(size_t)s3 * OUT_FT + fo];
#pragma unroll
        for (int i = 0; i < 8; i++) {
            accA[i] += bf2f(r0[i]) + bf2f(r1[i]);
            accB[i] += bf2f(r2[i]) + bf2f(r3[i]);
        }
    }
    if (j + 8 <= end) {
        int s0 = csr[j + g];
        int s1 = csr[j + 4 + g];
        u16x8 r0 = *(const u16x8*)&hs[(size_t)s0 * OUT_FT + fo];
        u16x8 r1 = *(const u16x8*)&hs[(size_t)s1 * OUT_FT + fo];
#pragma unroll
        for (int i = 0; i < 8; i++) accA[i] += bf2f(r0[i]) + bf2f(r1[i]);
        j += 8;
    }
    for (; j < end; j += 4) {
        int idx = j + g;
        if (idx < end) {
            int s = csr[idx];
            u16x8 r0 = *(const u16x8*)&hs[(size_t)s * OUT_FT + fo];
#pragma unroll
            for (int i = 0; i < 8; i++) accB[i] += bf2f(r0[i]);
        }
    }
#pragma unroll
    for (int i = 0; i < 8; i++) {
        float v = accA[i] + accB[i];
        v += __shfl_xor(v, 8, 64);
        v += __shfl_xor(v, 16, 64);
        accA[i] = v;
    }
    if (g == 0) {
        u16x8 sr = *(const u16x8*)&hs[(size_t)node * OUT_FT + fo];
        float dv = dinv[node];
        f32x4 b0 = *(const f32x4*)&b[fo];
        f32x4 b1 = *(const f32x4*)&b[fo + 4];
        f32x4 o0, o1;
#pragma unroll
        for (int i = 0; i < 4; i++) {
            o0[i] = dv * (accA[i]     + bf2f(sr[i]))     + b0[i];
            o1[i] = dv * (accA[4 + i] + bf2f(sr[4 + i])) + b1[i];
        }
        *(f32x4*)&out[(size_t)node * OUT_FT + fo] = o0;
        *(f32x4*)&out[(size_t)node * OUT_FT + fo + 4] = o1;
    }
}

// ================= standalone wrappers (fallback path) =================

__global__ __launch_bounds__(256) void k_bin(const int* srcA, const int* dstA,
        int* gcur, unsigned* pairs, const float* W1, const float* W2,
        u16* W1t, u16* W2t) {
    __shared__ int lh[NBUK];
    dev_bin(blockIdx.x, threadIdx.x, lh, srcA, dstA, gcur, pairs, W1, W2, W1t, W2t);
}

__global__ __launch_bounds__(256) void k_fillB(const unsigned* pairs, const int* gcnt,
        int* offsets, float* dinv, int* csr) {
    __shared__ int shm[NPB + 256 + 1];
    dev_fillB(blockIdx.x, threadIdx.x, shm, pairs, gcnt, offsets, dinv, csr);
}

__global__ __launch_bounds__(256) void k_gemm1(const float* A, const u16* Bt,
        const float* dinv, u16* C) {
    __shared__ __align__(16) char smem[30720];
    dev_gemm1(blockIdx.x, threadIdx.x, smem, A, Bt, dinv, C);
}

__global__ __launch_bounds__(256) void k_gemm2(const u16* A, const u16* Bt,
        const float* dinv, u16* C) {
    __shared__ __align__(16) char smem[20480];
    dev_gemm2(blockIdx.x, threadIdx.x, smem, A, Bt, dinv, C);
}

__global__ __launch_bounds__(256) void k_agg1(const u16* hs, const int* offsets,
        const int* csr, const float* dinv, const float* b, u16* out) {
    dev_agg1(blockIdx.x, threadIdx.x, hs, offsets, csr, dinv, b, out);
}

__global__ __launch_bounds__(256) void k_agg2(const u16* hs, const int* offsets,
        const int* csr, const float* dinv, const float* b, float* out) {
    dev_agg2(blockIdx.x, threadIdx.x, hs, offsets, csr, dinv, b, out);
}

// ================= cooperative mega-kernel =================
// All 6 phases, grid-stride, separated by grid.sync(). Grid is sized by the
// occupancy API at launch; any grid size is correct.

__global__ __launch_bounds__(256) void k_mega(const float* x, const int* ei,
        const float* W1, const float* b1, const float* W2, const float* b2,
        float* out, char* ws) {
    cg::grid_group grid = cg::this_grid();
    __shared__ __align__(16) char smem[30720];
    const int bid = blockIdx.x, t = threadIdx.x, G = gridDim.x;

    int*      offsets = (int*)(ws + 0);
    float*    dinv    = (float*)(ws + 400512);
    int*      csr     = (int*)(ws + 800512);
    u16*      W1t     = (u16*)(ws + 7200512);
    u16*      W2t     = (u16*)(ws + 7266048);
    int*      gcur    = (int*)(ws + 7282432);
    u16*      hs1     = (u16*)(ws + 7284608);
    u16*      a1      = (u16*)(ws + 32884608);
    unsigned* pairs   = (unsigned*)(ws + 32884608);  // aliases a1; phases disjoint
    u16*      hs2     = hs1;                          // hs1 dead after agg1 phase
    const int* srcA = ei;
    const int* dstA = ei + N_EDGES;

    for (int vb = bid; vb < G_BIN + G_CAST; vb += G)
        dev_bin(vb, t, (int*)smem, srcA, dstA, gcur, pairs, W1, W2, W1t, W2t);
    __threadfence(); grid.sync();

    for (int vb = bid; vb < NBUK; vb += G)
        dev_fillB(vb, t, (int*)smem, pairs, gcur, offsets, dinv, csr);
    __threadfence(); grid.sync();

    for (int vb = bid; vb < G_GEMM; vb += G)
        dev_gemm1(vb, t, smem, x, W1t, dinv, hs1);
    __threadfence(); grid.sync();

    for (int vb = bid; vb < G_AGG; vb += G)
        dev_agg1(vb, t, hs1, offsets, csr, dinv, b1, a1);
    __threadfence(); grid.sync();

    for (int vb = bid; vb < G_GEMM; vb += G)
        dev_gemm2(vb, t, smem, a1, W2t, dinv, hs2);
    __threadfence(); grid.sync();

    for (int vb = bid; vb < G_AGG; vb += G)
        dev_agg2(vb, t, hs2, offsets, csr, dinv, b2, out);
}

// ================= launch =================

extern "C" void kernel_launch(void* const* d_in, const int* in_sizes, int n_in,
                              void* d_out, int out_size, void* d_ws, size_t ws_size,
                              hipStream_t stream) {
    const float* x  = (const float*)d_in[0];
    const int*   ei = (const int*)d_in[1];  // [2][E]
    const float* W1 = (const float*)d_in[2];
    const float* b1 = (const float*)d_in[3];
    const float* W2 = (const float*)d_in[4];
    const float* b2 = (const float*)d_in[5];
    float* out = (float*)d_out;

    char* ws = (char*)d_ws;
    int*      offsets = (int*)(ws + 0);          // (N+1) ints -> 400512
    float*    dinv    = (float*)(ws + 400512);   // N floats   -> 800512
    int*      csr     = (int*)(ws + 800512);     // E ints     -> 7200512
    u16*      W1t     = (u16*)(ws + 7200512);    // 128x256    -> 7266048
    u16*      W2t     = (u16*)(ws + 7266048);    // 64x128     -> 7282432
    int*      gcur    = (int*)(ws + 7282432);    // 256 ints   -> 7283456
    u16*      hs1     = (u16*)(ws + 7284608);    // N*128 bf16 -> 32884608
    u16*      a1      = (u16*)(ws + 32884608);   // N*128 bf16 -> 58484608
    unsigned* pairs   = (unsigned*)(ws + 32884608); // 8 MB packed, dead before agg1
    u16*      hs2     = hs1;                     // hs1 dead after agg1

    const int* srcA = ei;
    const int* dstA = ei + N_EDGES;

    hipMemsetAsync(gcur, 0, NBUK * sizeof(int), stream);

    // Cooperative single-launch, sized by the occupancy API; fall back to the
    // proven multi-dispatch path on ANY error (round-4 lesson: never trust an
    // unchecked cooperative launch).
    int nb = 0;
    hipError_t qerr = hipOccupancyMaxActiveBlocksPerMultiprocessor(&nb, k_mega, 256, 0);
    int ncu = 0;
    if (hipDeviceGetAttribute(&ncu, hipDeviceAttributeMultiprocessorCount, 0) != hipSuccess || ncu <= 0)
        ncu = 256;
    hipError_t lerr = hipErrorInvalidValue;
    if (qerr == hipSuccess && nb > 0) {
        int grid = nb * ncu;
        void* kargs[] = { (void*)&x, (void*)&ei, (void*)&W1, (void*)&b1, (void*)&W2,
                          (void*)&b2, (void*)&out, (void*)&ws };
        lerr = hipLaunchCooperativeKernel(k_mega, dim3(grid), dim3(256), kargs, 0, stream);
    }
    if (lerr != hipSuccess) {
        // fallback: round-8 multi-dispatch pipeline (identical phase bodies)
        k_bin<<<G_BIN + G_CAST, 256, 0, stream>>>(srcA, dstA, gcur, pairs, W1, W2, W1t, W2t);
        k_fillB<<<NBUK, 256, 0, stream>>>(pairs, gcur, offsets, dinv, csr);
        k_gemm1<<<G_GEMM, 256, 0, stream>>>(x, W1t, dinv, hs1);
        k_agg1<<<G_AGG, 256, 0, stream>>>(hs1, offsets, csr, dinv, b1, a1);
        k_gemm2<<<G_GEMM, 256, 0, stream>>>(a1, W2t, dinv, hs2);
        k_agg2<<<G_AGG, 256, 0, stream>>>(hs2, offsets, csr, dinv, b2, out);
    }
}